// Round 1
// baseline (752.710 us; speedup 1.0000x reference)
//
#include <hip/hip_runtime.h>

typedef unsigned short ushort_t;
typedef unsigned int uint_t;

typedef short bf16x8 __attribute__((ext_vector_type(8)));
typedef float f32x4 __attribute__((ext_vector_type(4)));

#define DIM 128

__device__ __forceinline__ float bf2f(ushort_t u) {
    uint_t x = ((uint_t)u) << 16;
    float f;
    __builtin_memcpy(&f, &x, 4);
    return f;
}

__device__ __forceinline__ ushort_t f2bf(float f) {
    uint_t x;
    __builtin_memcpy(&x, &f, 4);
    uint_t r = (x + 0x7fffu + ((x >> 16) & 1u)) >> 16;
    return (ushort_t)r;
}

// ---------- conversion kernels ----------

__global__ void k_cvt_f32_bf16(const float* __restrict__ in, ushort_t* __restrict__ out, int n4) {
    int i = blockIdx.x * blockDim.x + threadIdx.x;
    if (i < n4) {
        float4 f = ((const float4*)in)[i];
        ushort4 u;
        u.x = f2bf(f.x); u.y = f2bf(f.y); u.z = f2bf(f.z); u.w = f2bf(f.w);
        ((ushort4*)out)[i] = u;
    }
}

// WT[n*128+k] = bf16(W[k*128+n])  (pre-transposed weights for B-fragment loads)
__global__ void k_wt(const float* __restrict__ W, ushort_t* __restrict__ WT) {
    int i = blockIdx.x * blockDim.x + threadIdx.x;  // 16384
    int n = i >> 7, k = i & 127;
    WT[i] = f2bf(W[k * DIM + n]);
}

// ---------- CSR build ----------

__global__ void k_deg(const int* __restrict__ dst, int E, int* __restrict__ deg) {
    int i = blockIdx.x * blockDim.x + threadIdx.x;
    if (i < E) atomicAdd(&deg[dst[i]], 1);
}

__global__ void k_scan_chunks(const int* __restrict__ deg, int n,
                              int* __restrict__ excl, int* __restrict__ bsum) {
    __shared__ int lds[1024];
    int t = threadIdx.x;
    int i = blockIdx.x * 1024 + t;
    int v = (i < n) ? deg[i] : 0;
    lds[t] = v;
    __syncthreads();
    for (int off = 1; off < 1024; off <<= 1) {
        int u = (t >= off) ? lds[t - off] : 0;
        __syncthreads();
        lds[t] += u;
        __syncthreads();
    }
    if (i < n) excl[i] = lds[t] - v;
    if (t == 1023) bsum[blockIdx.x] = lds[1023];
}

__global__ void k_scan_tops(const int* __restrict__ bsum, int nc, int* __restrict__ boff) {
    __shared__ int lds[128];
    int t = threadIdx.x;
    int v = (t < nc) ? bsum[t] : 0;
    lds[t] = v;
    __syncthreads();
    for (int off = 1; off < 128; off <<= 1) {
        int u = (t >= off) ? lds[t - off] : 0;
        __syncthreads();
        lds[t] += u;
        __syncthreads();
    }
    boff[t] = lds[t] - v;
}

__global__ void k_finalize(const int* __restrict__ excl, const int* __restrict__ boff,
                           int n, int E, int* __restrict__ row_ptr, int* __restrict__ cursor) {
    int i = blockIdx.x * blockDim.x + threadIdx.x;
    if (i < n) {
        int v = excl[i] + boff[i >> 10];
        row_ptr[i] = v;
        cursor[i] = v;
        if (i == 0) row_ptr[n] = E;
    }
}

__global__ void k_fill(const int* __restrict__ src, const int* __restrict__ dst, int E,
                       int* __restrict__ cursor, int* __restrict__ csr_src) {
    int i = blockIdx.x * blockDim.x + threadIdx.x;
    if (i < E) {
        int p = atomicAdd(&cursor[dst[i]], 1);
        csr_src[p] = src[i];
    }
}

// ---------- mean aggregation: one wave per node, bf16 rows, fp32 accumulate ----------

__global__ __launch_bounds__(256) void k_agg(const ushort_t* __restrict__ X,
                                             const int* __restrict__ row_ptr,
                                             const int* __restrict__ csr,
                                             ushort_t* __restrict__ out, int n) {
    int wave = (int)((blockIdx.x * (unsigned)blockDim.x + threadIdx.x) >> 6);
    if (wave >= n) return;
    int lane = threadIdx.x & 63;
    int beg = row_ptr[wave], end = row_ptr[wave + 1];
    float a0 = 0.f, a1 = 0.f;
    for (int e = beg; e < end; e++) {
        int s = csr[e];
        uint_t p = *(const uint_t*)(X + (size_t)s * DIM + lane * 2);
        a0 += bf2f((ushort_t)(p & 0xffffu));
        a1 += bf2f((ushort_t)(p >> 16));
    }
    int cnt = end - beg;
    float sc = (cnt > 0) ? 1.f / (float)cnt : 0.f;
    uint_t pk = (uint_t)f2bf(a0 * sc) | ((uint_t)f2bf(a1 * sc) << 16);
    *(uint_t*)(out + (size_t)wave * DIM + lane * 2) = pk;
}

// ---------- fused GEMM: out = A1*W_l^T' + A2*W_r^T' + b  (K=128 each, N=128) ----------
// WTl/WTr stored as [n][k] bf16 (pre-transposed). One wave computes 16 rows x 128 cols.
// MFMA 16x16x32 bf16 layouts (m89-verified):
//   A frag: lane holds A[m=lane&15][k=quad*8+j]
//   B frag: lane holds B[k=quad*8+j][n=lane&15] = WT[n=lane&15][k=quad*8+j]
//   C/D   : col=lane&15, row=quad*4+reg

template <bool RELU, bool OUT_BF16>
__global__ __launch_bounds__(256) void k_gemm(const ushort_t* __restrict__ A1,
                                              const ushort_t* __restrict__ A2,
                                              const ushort_t* __restrict__ WTl,
                                              const ushort_t* __restrict__ WTr,
                                              const float* __restrict__ bias,
                                              void* __restrict__ Out, int n_tiles, int M) {
    int wave = (int)((blockIdx.x * (unsigned)blockDim.x + threadIdx.x) >> 6);
    if (wave >= n_tiles) return;
    int lane = threadIdx.x & 63;
    int col = lane & 15;
    int quad = lane >> 4;

    int arow = wave * 16 + col;  // A's m index comes from lane&15
    const ushort_t* a1p = A1 + (size_t)arow * DIM + quad * 8;
    const ushort_t* a2p = A2 + (size_t)arow * DIM + quad * 8;

    bf16x8 a[8];
#pragma unroll
    for (int ks = 0; ks < 4; ks++) a[ks] = *(const bf16x8*)(a1p + ks * 32);
#pragma unroll
    for (int ks = 0; ks < 4; ks++) a[4 + ks] = *(const bf16x8*)(a2p + ks * 32);

    f32x4 acc[8];
#pragma unroll
    for (int nt = 0; nt < 8; nt++) acc[nt] = (f32x4){0.f, 0.f, 0.f, 0.f};

#pragma unroll
    for (int nt = 0; nt < 8; nt++) {
        const ushort_t* bl = WTl + (size_t)(nt * 16 + col) * DIM + quad * 8;
        const ushort_t* br = WTr + (size_t)(nt * 16 + col) * DIM + quad * 8;
#pragma unroll
        for (int ks = 0; ks < 4; ks++)
            acc[nt] = __builtin_amdgcn_mfma_f32_16x16x32_bf16(a[ks], *(const bf16x8*)(bl + ks * 32), acc[nt], 0, 0, 0);
#pragma unroll
        for (int ks = 0; ks < 4; ks++)
            acc[nt] = __builtin_amdgcn_mfma_f32_16x16x32_bf16(a[4 + ks], *(const bf16x8*)(br + ks * 32), acc[nt], 0, 0, 0);
    }

#pragma unroll
    for (int nt = 0; nt < 8; nt++) {
        int c = nt * 16 + col;
        float bv = bias[c];
#pragma unroll
        for (int r = 0; r < 4; r++) {
            int m = wave * 16 + quad * 4 + r;
            if (m < M) {
                float v = acc[nt][r] + bv;
                if (RELU) v = v > 0.f ? v : 0.f;
                if (OUT_BF16)
                    ((ushort_t*)Out)[(size_t)m * DIM + c] = f2bf(v);
                else
                    ((float*)Out)[(size_t)m * DIM + c] = v;
            }
        }
    }
}

// ---------- host ----------

extern "C" void kernel_launch(void* const* d_in, const int* in_sizes, int n_in,
                              void* d_out, int out_size, void* d_ws, size_t ws_size,
                              hipStream_t stream) {
    const int N = in_sizes[0] / DIM;   // 100000
    const int E = in_sizes[1] / 2;     // 1600000

    const float* x   = (const float*)d_in[0];
    const int*   ei  = (const int*)d_in[1];
    const int*   src = ei;
    const int*   dst = ei + E;
    const float* W1l = (const float*)d_in[2];
    const float* b1  = (const float*)d_in[3];
    const float* W1r = (const float*)d_in[4];
    const float* W2l = (const float*)d_in[5];
    const float* b2  = (const float*)d_in[6];
    const float* W2r = (const float*)d_in[7];
    float* out = (float*)d_out;

    char* ws = (char*)d_ws;
    size_t off = 0;
    auto alloc = [&](size_t bytes) -> char* {
        char* p = ws + off;
        off = (off + bytes + 255) & ~(size_t)255;
        return p;
    };

    const int nc = (N + 1023) / 1024;                 // scan chunks (98)
    int*      deg     = (int*)alloc((size_t)N * 4);
    int*      excl    = (int*)alloc((size_t)N * 4);
    int*      bsum    = (int*)alloc(128 * 4);
    int*      boff    = (int*)alloc(132 * 4);
    int*      row_ptr = (int*)alloc((size_t)(N + 1) * 4);
    int*      cursor  = (int*)alloc((size_t)N * 4);
    int*      csr     = (int*)alloc((size_t)E * 4);
    size_t    fpad    = (size_t)16 * DIM * 2;         // tile-padding for MFMA A loads
    ushort_t* xb      = (ushort_t*)alloc((size_t)N * DIM * 2 + fpad);
    ushort_t* hb      = (ushort_t*)alloc((size_t)N * DIM * 2 + fpad);
    ushort_t* aggb    = (ushort_t*)alloc((size_t)N * DIM * 2 + fpad);
    ushort_t* wt1l    = (ushort_t*)alloc((size_t)DIM * DIM * 2);
    ushort_t* wt1r    = (ushort_t*)alloc((size_t)DIM * DIM * 2);
    ushort_t* wt2l    = (ushort_t*)alloc((size_t)DIM * DIM * 2);
    ushort_t* wt2r    = (ushort_t*)alloc((size_t)DIM * DIM * 2);

    // zero degree histogram (ws is poisoned each call)
    hipMemsetAsync(deg, 0, (size_t)N * 4, stream);

    // x -> bf16
    {
        int n4 = N * DIM / 4;
        k_cvt_f32_bf16<<<dim3((n4 + 255) / 256), dim3(256), 0, stream>>>(x, xb, n4);
    }
    // weights -> transposed bf16
    {
        dim3 g((DIM * DIM + 255) / 256), b(256);
        k_wt<<<g, b, 0, stream>>>(W1l, wt1l);
        k_wt<<<g, b, 0, stream>>>(W1r, wt1r);
        k_wt<<<g, b, 0, stream>>>(W2l, wt2l);
        k_wt<<<g, b, 0, stream>>>(W2r, wt2r);
    }
    // CSR build
    k_deg<<<dim3((E + 255) / 256), dim3(256), 0, stream>>>(dst, E, deg);
    k_scan_chunks<<<dim3(nc), dim3(1024), 0, stream>>>(deg, N, excl, bsum);
    k_scan_tops<<<dim3(1), dim3(128), 0, stream>>>(bsum, nc, boff);
    k_finalize<<<dim3((N + 255) / 256), dim3(256), 0, stream>>>(excl, boff, N, E, row_ptr, cursor);
    k_fill<<<dim3((E + 255) / 256), dim3(256), 0, stream>>>(src, dst, E, cursor, csr);

    const int n_tiles = (N + 15) / 16;                          // 6250
    dim3 gemm_grid((n_tiles + 3) / 4), gemm_blk(256);
    dim3 agg_grid((N + 3) / 4), agg_blk(256);                   // one wave per node

    // layer 1
    k_agg<<<agg_grid, agg_blk, 0, stream>>>(xb, row_ptr, csr, aggb, N);
    k_gemm<true, true><<<gemm_grid, gemm_blk, 0, stream>>>(aggb, xb, wt1l, wt1r, b1, hb, n_tiles, N);
    // layer 2
    k_agg<<<agg_grid, agg_blk, 0, stream>>>(hb, row_ptr, csr, aggb, N);
    k_gemm<false, false><<<gemm_grid, gemm_blk, 0, stream>>>(aggb, hb, wt2l, wt2r, b2, out, n_tiles, N);

    (void)n_in; (void)out_size; (void)ws_size;
}

// Round 2
// 517.819 us; speedup vs baseline: 1.4536x; 1.4536x over previous
//
#include <hip/hip_runtime.h>

typedef unsigned short ushort_t;
typedef unsigned int uint_t;

typedef short bf16x8 __attribute__((ext_vector_type(8)));
typedef float f32x4 __attribute__((ext_vector_type(4)));

#define DIM 128

__device__ __forceinline__ float bf2f(ushort_t u) {
    uint_t x = ((uint_t)u) << 16;
    float f;
    __builtin_memcpy(&f, &x, 4);
    return f;
}

__device__ __forceinline__ ushort_t f2bf(float f) {
    uint_t x;
    __builtin_memcpy(&x, &f, 4);
    uint_t r = (x + 0x7fffu + ((x >> 16) & 1u)) >> 16;
    return (ushort_t)r;
}

// ---------- conversion kernels ----------

__global__ void k_cvt_f32_bf16(const float* __restrict__ in, ushort_t* __restrict__ out, int n4) {
    int i = blockIdx.x * blockDim.x + threadIdx.x;
    if (i < n4) {
        float4 f = ((const float4*)in)[i];
        ushort4 u;
        u.x = f2bf(f.x); u.y = f2bf(f.y); u.z = f2bf(f.z); u.w = f2bf(f.w);
        ((ushort4*)out)[i] = u;
    }
}

// all four weight transposes in one launch: WT[n*128+k] = bf16(W[k*128+n])
__global__ void k_wt4(const float* __restrict__ W0, const float* __restrict__ W1,
                      const float* __restrict__ W2, const float* __restrict__ W3,
                      ushort_t* __restrict__ T0, ushort_t* __restrict__ T1,
                      ushort_t* __restrict__ T2, ushort_t* __restrict__ T3) {
    int i = blockIdx.x * blockDim.x + threadIdx.x;  // 4*16384
    int w = i >> 14, j = i & 16383;
    int n = j >> 7, k = j & 127;
    const float* W = (w == 0) ? W0 : (w == 1) ? W1 : (w == 2) ? W2 : W3;
    ushort_t* T = (w == 0) ? T0 : (w == 1) ? T1 : (w == 2) ? T2 : T3;
    T[j] = f2bf(W[k * DIM + n]);
}

// ---------- CSR build ----------

__global__ void k_deg(const int* __restrict__ dst, int E, int* __restrict__ deg) {
    int i = blockIdx.x * blockDim.x + threadIdx.x;
    if (i < E) atomicAdd(&deg[dst[i]], 1);
}

__global__ void k_scan_chunks(const int* __restrict__ deg, int n,
                              int* __restrict__ excl, int* __restrict__ bsum) {
    __shared__ int lds[1024];
    int t = threadIdx.x;
    int i = blockIdx.x * 1024 + t;
    int v = (i < n) ? deg[i] : 0;
    lds[t] = v;
    __syncthreads();
    for (int off = 1; off < 1024; off <<= 1) {
        int u = (t >= off) ? lds[t - off] : 0;
        __syncthreads();
        lds[t] += u;
        __syncthreads();
    }
    if (i < n) excl[i] = lds[t] - v;
    if (t == 1023) bsum[blockIdx.x] = lds[1023];
}

__global__ void k_scan_tops(const int* __restrict__ bsum, int nc, int* __restrict__ boff) {
    __shared__ int lds[128];
    int t = threadIdx.x;
    int v = (t < nc) ? bsum[t] : 0;
    lds[t] = v;
    __syncthreads();
    for (int off = 1; off < 128; off <<= 1) {
        int u = (t >= off) ? lds[t - off] : 0;
        __syncthreads();
        lds[t] += u;
        __syncthreads();
    }
    boff[t] = lds[t] - v;
}

__global__ void k_finalize(const int* __restrict__ excl, const int* __restrict__ boff,
                           int n, int E, int* __restrict__ row_ptr, int* __restrict__ cursor) {
    int i = blockIdx.x * blockDim.x + threadIdx.x;
    if (i < n) {
        int v = excl[i] + boff[i >> 10];
        row_ptr[i] = v;
        cursor[i] = v;
        if (i == 0) row_ptr[n] = E;
    }
}

__global__ void k_fill(const int* __restrict__ src, const int* __restrict__ dst, int E,
                       int* __restrict__ cursor, int* __restrict__ csr_src) {
    int i = blockIdx.x * blockDim.x + threadIdx.x;
    if (i < E) {
        int p = atomicAdd(&cursor[dst[i]], 1);
        csr_src[p] = src[i];
    }
}

// ---------- mean aggregation v2 ----------
// 16 lanes per node (4 nodes/wave), 16 B (8 bf16) per lane per row, edge loop
// unrolled x4 with batched csr loads -> up to 16 outstanding row loads/wave.

__device__ __forceinline__ void acc8(float* a, uint4 p) {
    a[0] += bf2f((ushort_t)(p.x & 0xffffu));
    a[1] += bf2f((ushort_t)(p.x >> 16));
    a[2] += bf2f((ushort_t)(p.y & 0xffffu));
    a[3] += bf2f((ushort_t)(p.y >> 16));
    a[4] += bf2f((ushort_t)(p.z & 0xffffu));
    a[5] += bf2f((ushort_t)(p.z >> 16));
    a[6] += bf2f((ushort_t)(p.w & 0xffffu));
    a[7] += bf2f((ushort_t)(p.w >> 16));
}

__global__ __launch_bounds__(256) void k_agg(const ushort_t* __restrict__ X,
                                             const int* __restrict__ row_ptr,
                                             const int* __restrict__ csr,
                                             ushort_t* __restrict__ out, int n) {
    int node = (int)((blockIdx.x * (unsigned)blockDim.x + threadIdx.x) >> 4);
    if (node >= n) return;
    int sl = threadIdx.x & 15;               // sub-lane: 8 bf16 = 16 B of the row
    int beg = row_ptr[node], end = row_ptr[node + 1];
    float a[8] = {0.f, 0.f, 0.f, 0.f, 0.f, 0.f, 0.f, 0.f};

    int e = beg;
    for (; e + 4 <= end; e += 4) {
        int s0 = csr[e + 0], s1 = csr[e + 1], s2 = csr[e + 2], s3 = csr[e + 3];
        uint4 p0 = *(const uint4*)(X + (size_t)s0 * DIM + sl * 8);
        uint4 p1 = *(const uint4*)(X + (size_t)s1 * DIM + sl * 8);
        uint4 p2 = *(const uint4*)(X + (size_t)s2 * DIM + sl * 8);
        uint4 p3 = *(const uint4*)(X + (size_t)s3 * DIM + sl * 8);
        acc8(a, p0); acc8(a, p1); acc8(a, p2); acc8(a, p3);
    }
    for (; e < end; e++) {
        int s = csr[e];
        uint4 p = *(const uint4*)(X + (size_t)s * DIM + sl * 8);
        acc8(a, p);
    }

    int cnt = end - beg;
    float sc = (cnt > 0) ? 1.f / (float)cnt : 0.f;
    uint4 o;
    o.x = (uint_t)f2bf(a[0] * sc) | ((uint_t)f2bf(a[1] * sc) << 16);
    o.y = (uint_t)f2bf(a[2] * sc) | ((uint_t)f2bf(a[3] * sc) << 16);
    o.z = (uint_t)f2bf(a[4] * sc) | ((uint_t)f2bf(a[5] * sc) << 16);
    o.w = (uint_t)f2bf(a[6] * sc) | ((uint_t)f2bf(a[7] * sc) << 16);
    *(uint4*)(out + (size_t)node * DIM + sl * 8) = o;
}

// ---------- fused GEMM: out = A1*W_l + A2*W_r + b, 32 rows per wave ----------
// MFMA 16x16x32 bf16 layouts (m89-verified):
//   A frag: lane holds A[m=lane&15][k=quad*8+j]
//   B frag: lane holds B[k=quad*8+j][n=lane&15] = WT[n=lane&15][k=quad*8+j]
//   C/D   : col=lane&15, row=quad*4+reg

template <bool RELU, bool OUT_BF16>
__global__ __launch_bounds__(256) void k_gemm(const ushort_t* __restrict__ A1,
                                              const ushort_t* __restrict__ A2,
                                              const ushort_t* __restrict__ WTl,
                                              const ushort_t* __restrict__ WTr,
                                              const float* __restrict__ bias,
                                              void* __restrict__ Out, int n_waves, int M) {
    int wave = (int)((blockIdx.x * (unsigned)blockDim.x + threadIdx.x) >> 6);
    if (wave >= n_waves) return;
    int lane = threadIdx.x & 63;
    int col = lane & 15;
    int quad = lane >> 4;

    // two 16-row M-tiles per wave
    bf16x8 a[2][8];
#pragma unroll
    for (int t = 0; t < 2; t++) {
        int arow = wave * 32 + t * 16 + col;
        const ushort_t* a1p = A1 + (size_t)arow * DIM + quad * 8;
        const ushort_t* a2p = A2 + (size_t)arow * DIM + quad * 8;
#pragma unroll
        for (int ks = 0; ks < 4; ks++) a[t][ks] = *(const bf16x8*)(a1p + ks * 32);
#pragma unroll
        for (int ks = 0; ks < 4; ks++) a[t][4 + ks] = *(const bf16x8*)(a2p + ks * 32);
    }

    f32x4 acc[2][8];
#pragma unroll
    for (int t = 0; t < 2; t++)
#pragma unroll
        for (int nt = 0; nt < 8; nt++) acc[t][nt] = (f32x4){0.f, 0.f, 0.f, 0.f};

#pragma unroll
    for (int nt = 0; nt < 8; nt++) {
        const ushort_t* bl = WTl + (size_t)(nt * 16 + col) * DIM + quad * 8;
        const ushort_t* br = WTr + (size_t)(nt * 16 + col) * DIM + quad * 8;
#pragma unroll
        for (int ks = 0; ks < 4; ks++) {
            bf16x8 b = *(const bf16x8*)(bl + ks * 32);
            acc[0][nt] = __builtin_amdgcn_mfma_f32_16x16x32_bf16(a[0][ks], b, acc[0][nt], 0, 0, 0);
            acc[1][nt] = __builtin_amdgcn_mfma_f32_16x16x32_bf16(a[1][ks], b, acc[1][nt], 0, 0, 0);
        }
#pragma unroll
        for (int ks = 0; ks < 4; ks++) {
            bf16x8 b = *(const bf16x8*)(br + ks * 32);
            acc[0][nt] = __builtin_amdgcn_mfma_f32_16x16x32_bf16(a[0][4 + ks], b, acc[0][nt], 0, 0, 0);
            acc[1][nt] = __builtin_amdgcn_mfma_f32_16x16x32_bf16(a[1][4 + ks], b, acc[1][nt], 0, 0, 0);
        }
    }

#pragma unroll
    for (int t = 0; t < 2; t++)
#pragma unroll
        for (int nt = 0; nt < 8; nt++) {
            int c = nt * 16 + col;
            float bv = bias[c];
#pragma unroll
            for (int r = 0; r < 4; r++) {
                int m = wave * 32 + t * 16 + quad * 4 + r;
                if (m < M) {
                    float v = acc[t][nt][r] + bv;
                    if (RELU) v = v > 0.f ? v : 0.f;
                    if (OUT_BF16)
                        ((ushort_t*)Out)[(size_t)m * DIM + c] = f2bf(v);
                    else
                        ((float*)Out)[(size_t)m * DIM + c] = v;
                }
            }
        }
}

// ---------- host ----------

extern "C" void kernel_launch(void* const* d_in, const int* in_sizes, int n_in,
                              void* d_out, int out_size, void* d_ws, size_t ws_size,
                              hipStream_t stream) {
    const int N = in_sizes[0] / DIM;   // 100000
    const int E = in_sizes[1] / 2;     // 1600000

    const float* x   = (const float*)d_in[0];
    const int*   ei  = (const int*)d_in[1];
    const int*   src = ei;
    const int*   dst = ei + E;
    const float* W1l = (const float*)d_in[2];
    const float* b1  = (const float*)d_in[3];
    const float* W1r = (const float*)d_in[4];
    const float* W2l = (const float*)d_in[5];
    const float* b2  = (const float*)d_in[6];
    const float* W2r = (const float*)d_in[7];
    float* out = (float*)d_out;

    char* ws = (char*)d_ws;
    size_t off = 0;
    auto alloc = [&](size_t bytes) -> char* {
        char* p = ws + off;
        off = (off + bytes + 255) & ~(size_t)255;
        return p;
    };

    const int nc = (N + 1023) / 1024;                 // scan chunks (98)
    int*      deg     = (int*)alloc((size_t)N * 4);
    int*      excl    = (int*)alloc((size_t)N * 4);
    int*      bsum    = (int*)alloc(128 * 4);
    int*      boff    = (int*)alloc(132 * 4);
    int*      row_ptr = (int*)alloc((size_t)(N + 1) * 4);
    int*      cursor  = (int*)alloc((size_t)N * 4);
    int*      csr     = (int*)alloc((size_t)E * 4);
    size_t    fpad    = (size_t)32 * DIM * 2;         // tile-padding for MFMA A loads
    ushort_t* xb      = (ushort_t*)alloc((size_t)N * DIM * 2 + fpad);
    ushort_t* hb      = (ushort_t*)alloc((size_t)N * DIM * 2 + fpad);
    ushort_t* aggb    = (ushort_t*)alloc((size_t)N * DIM * 2 + fpad);
    ushort_t* wt1l    = (ushort_t*)alloc((size_t)DIM * DIM * 2);
    ushort_t* wt1r    = (ushort_t*)alloc((size_t)DIM * DIM * 2);
    ushort_t* wt2l    = (ushort_t*)alloc((size_t)DIM * DIM * 2);
    ushort_t* wt2r    = (ushort_t*)alloc((size_t)DIM * DIM * 2);

    // zero degree histogram (ws is poisoned each call)
    hipMemsetAsync(deg, 0, (size_t)N * 4, stream);

    // x -> bf16
    {
        int n4 = N * DIM / 4;
        k_cvt_f32_bf16<<<dim3((n4 + 255) / 256), dim3(256), 0, stream>>>(x, xb, n4);
    }
    // weights -> transposed bf16 (single launch)
    k_wt4<<<dim3(4 * DIM * DIM / 256), dim3(256), 0, stream>>>(W1l, W1r, W2l, W2r,
                                                               wt1l, wt1r, wt2l, wt2r);
    // CSR build
    k_deg<<<dim3((E + 255) / 256), dim3(256), 0, stream>>>(dst, E, deg);
    k_scan_chunks<<<dim3(nc), dim3(1024), 0, stream>>>(deg, N, excl, bsum);
    k_scan_tops<<<dim3(1), dim3(128), 0, stream>>>(bsum, nc, boff);
    k_finalize<<<dim3((N + 255) / 256), dim3(256), 0, stream>>>(excl, boff, N, E, row_ptr, cursor);
    k_fill<<<dim3((E + 255) / 256), dim3(256), 0, stream>>>(src, dst, E, cursor, csr);

    const int n_waves = (N + 31) / 32;                          // 3125 (32 rows/wave)
    dim3 gemm_grid((n_waves + 3) / 4), gemm_blk(256);
    dim3 agg_grid((N + 15) / 16), agg_blk(256);                 // 16 nodes/block (16 lanes/node)

    // layer 1
    k_agg<<<agg_grid, agg_blk, 0, stream>>>(xb, row_ptr, csr, aggb, N);
    k_gemm<true, true><<<gemm_grid, gemm_blk, 0, stream>>>(aggb, xb, wt1l, wt1r, b1, hb, n_waves, N);
    // layer 2
    k_agg<<<agg_grid, agg_blk, 0, stream>>>(hb, row_ptr, csr, aggb, N);
    k_gemm<false, false><<<gemm_grid, gemm_blk, 0, stream>>>(aggb, hb, wt2l, wt2r, b2, out, n_waves, N);

    (void)n_in; (void)out_size; (void)ws_size;
}